// Round 6
// baseline (977.844 us; speedup 1.0000x reference)
//
#include <hip/hip_runtime.h>
#include <stdint.h>

#define NN 50000
#define NE 1600000
#define FI 512
#define DD 512
#define NC 40
#define HW 1536
#define NB 13            // column buckets: bucket = col >> 12, window 4096 rows = 4MB (~L2/XCD)
#define NBN (NB * NN)    // 650000 bucket counters
#define SCAN_NBLK ((NBN + 1023) / 1024)  // 635

typedef __attribute__((ext_vector_type(8))) short short8;
typedef __attribute__((ext_vector_type(4))) float float4v;

static __device__ __forceinline__ unsigned short f2b(float f) {
    union { float f; unsigned int i; } v; v.f = f;
    unsigned int r = v.i + 0x7fffu + ((v.i >> 16) & 1u);
    return (unsigned short)(r >> 16);
}
static __device__ __forceinline__ float blo(unsigned int u) {
    union { unsigned int i; float f; } v; v.i = u << 16; return v.f;
}
static __device__ __forceinline__ float bhi(unsigned int u) {
    union { unsigned int i; float f; } v; v.i = u & 0xffff0000u; return v.f;
}
static __device__ __forceinline__ void async_copy16(void* lds, const void* g) {
    __builtin_amdgcn_global_load_lds((const __attribute__((address_space(1))) void*)g,
                                     (__attribute__((address_space(3))) void*)lds, 16, 0, 0);
}

// ---------------- x (fp32) -> bf16 dense [NN,512] ----------------
__global__ void convx_kernel(const float* __restrict__ x, unsigned short* __restrict__ dst) {
    int t = blockIdx.x * 256 + threadIdx.x;
    if (t >= NN * 64) return;
    const float* xf = x + (size_t)t * 8;
    float4 v0 = *(const float4*)(xf);
    float4 v1 = *(const float4*)(xf + 4);
    uint4 u;
    u.x = ((unsigned)f2b(v0.y) << 16) | f2b(v0.x);
    u.y = ((unsigned)f2b(v0.w) << 16) | f2b(v0.z);
    u.z = ((unsigned)f2b(v1.y) << 16) | f2b(v1.x);
    u.w = ((unsigned)f2b(v1.w) << 16) | f2b(v1.z);
    *(uint4*)(dst + (size_t)t * 8) = u;
}

// ---------------- CSR build (bucketed by col>>12 for gather locality) ----------------
__global__ void count_kernel(const int* __restrict__ row, const int* __restrict__ col,
                             int* cnt2, int* deg, int* __restrict__ rank) {
    int e = blockIdx.x * 256 + threadIdx.x;
    if (e < NE) {
        int r = row[e], c = col[e];
        rank[e] = atomicAdd(&cnt2[r * NB + (c >> 12)], 1);
        atomicAdd(&deg[c], 1);
    }
}

__global__ __launch_bounds__(1024) void scan1_kernel(const int* __restrict__ cnt,
                                                     int* __restrict__ excl, int* __restrict__ bsum) {
    __shared__ int buf[1024];
    int tid = threadIdx.x, gid = blockIdx.x * 1024 + tid;
    int v = (gid < NBN) ? cnt[gid] : 0;
    buf[tid] = v;
    __syncthreads();
    int acc = v;
    for (int off = 1; off < 1024; off <<= 1) {
        int t = (tid >= off) ? buf[tid - off] : 0;
        __syncthreads();
        acc += t;
        buf[tid] = acc;
        __syncthreads();
    }
    if (gid < NBN) excl[gid] = acc - v;
    if (tid == 1023) bsum[blockIdx.x] = acc;
}

// scan of SCAN_NBLK (=635) block sums in one 1024-thread block
__global__ __launch_bounds__(1024) void scan2_kernel(const int* __restrict__ bsum,
                                                     int* __restrict__ boff) {
    __shared__ int buf[1024];
    int tid = threadIdx.x;
    int orig = (tid < SCAN_NBLK) ? bsum[tid] : 0;
    buf[tid] = orig;
    __syncthreads();
    int acc = orig;
    for (int off = 1; off < 1024; off <<= 1) {
        int t = (tid >= off) ? buf[tid - off] : 0;
        __syncthreads();
        acc += t;
        buf[tid] = acc;
        __syncthreads();
    }
    if (tid < SCAN_NBLK) boff[tid] = acc - orig;
}

// finalize rp2 (+sentinel) and dinv
__global__ void scan3_kernel(int* __restrict__ rp2, const int* __restrict__ boff,
                             const int* __restrict__ deg, float* __restrict__ dinv) {
    int gid = blockIdx.x * 256 + threadIdx.x;
    if (gid < NBN) rp2[gid] += boff[gid >> 10];
    if (gid < NN)  dinv[gid] = rsqrtf((float)(deg[gid] + 1));
    if (gid == 0)  rp2[NBN] = NE;
}

// atomic-free placement: bucket-sorted within each row
__global__ void scatter_kernel(const int* __restrict__ row, const int* __restrict__ col,
                               const int* __restrict__ rp2, const int* __restrict__ rank,
                               int* __restrict__ cols_out) {
    int e = blockIdx.x * 256 + threadIdx.x;
    if (e < NE) {
        int r = row[e], c = col[e];
        cols_out[rp2[r * NB + (c >> 12)] + rank[e]] = c;
    }
}

// ---------------- weight prep ----------------
__global__ void transpose_kernel(const float* __restrict__ w, unsigned short* __restrict__ wt) {
    int t = blockIdx.x * 256 + threadIdx.x;   // 512*512
    int n = t & 511, k = t >> 9;
    wt[n * 512 + k] = f2b(w[(size_t)k * 512 + n]);
}

__global__ void wcat_kernel(const float* __restrict__ w2, unsigned short* __restrict__ wct) {
    int t = blockIdx.x * 256 + threadIdx.x;   // 48*1536
    int k = t % HW, n = t / HW;
    float v = 0.f;
    if (n < NC) {
        if (k < 512)       v = w2[(size_t)k * NC + n] + w2[(size_t)(k + 512) * NC + n];
        else if (k < 1024) v = w2[(size_t)(k + 512) * NC + n] + w2[(size_t)(k + 1024) * NC + n];
        else               v = w2[(size_t)(k + 1024) * NC + n];
    }
    wct[n * HW + k] = f2b(v);
}

// ---------------- GEMM1: t = relu(x@W1 + b1), dense in/out ----------------
__global__ __launch_bounds__(256) void gemm1_kernel(
    const unsigned short* __restrict__ xb, const unsigned short* __restrict__ w1t,
    const float* __restrict__ b1, unsigned short* __restrict__ tbuf) {
    __shared__ __align__(16) unsigned short As[128 * 32];
    __shared__ __align__(16) unsigned short Bs[128 * 32];
    const int tid = threadIdx.x;
    const int wave = tid >> 6, lane = tid & 63;
    const int q = lane >> 4, c = lane & 15;
    const int wm = wave & 1, wn = wave >> 1;
    const int m0 = blockIdx.x * 128, n0 = blockIdx.y * 128;

    float4v acc[4][4];
    for (int i = 0; i < 4; ++i)
        for (int j = 0; j < 4; ++j)
            acc[i][j] = (float4v){0.f, 0.f, 0.f, 0.f};

    for (int k0 = 0; k0 < FI; k0 += 32) {
        __syncthreads();
        #pragma unroll
        for (int h = 0; h < 2; ++h) {
            int chunk = h * 256 + wave * 64 + lane;
            int r = chunk >> 2, kc = chunk & 3;
            int gm = m0 + r; gm = gm < NN ? gm : NN - 1;
            async_copy16((char*)As + (size_t)(h * 256 + wave * 64) * 16,
                         xb + (size_t)gm * FI + k0 + kc * 8);
            async_copy16((char*)Bs + (size_t)(h * 256 + wave * 64) * 16,
                         w1t + (size_t)(n0 + r) * FI + k0 + kc * 8);
        }
        __syncthreads();
        short8 a[4], b[4];
        #pragma unroll
        for (int mi = 0; mi < 4; ++mi)
            a[mi] = *(const short8*)(As + ((wm * 64 + mi * 16 + c) * 32 + q * 8));
        #pragma unroll
        for (int ni = 0; ni < 4; ++ni)
            b[ni] = *(const short8*)(Bs + ((wn * 64 + ni * 16 + c) * 32 + q * 8));
        #pragma unroll
        for (int mi = 0; mi < 4; ++mi)
            #pragma unroll
            for (int ni = 0; ni < 4; ++ni)
                acc[mi][ni] = __builtin_amdgcn_mfma_f32_16x16x32_bf16(a[mi], b[ni], acc[mi][ni], 0, 0, 0);
    }
    #pragma unroll
    for (int ni = 0; ni < 4; ++ni) {
        int col = n0 + wn * 64 + ni * 16 + c;
        float bias = b1[col];
        #pragma unroll
        for (int mi = 0; mi < 4; ++mi) {
            int rbase = m0 + wm * 64 + mi * 16 + q * 4;
            #pragma unroll
            for (int r = 0; r < 4; ++r) {
                int row = rbase + r;
                if (row < NN) {
                    float v = acc[mi][ni][r] + bias;
                    tbuf[(size_t)row * FI + col] = f2b(v > 0.f ? v : 0.f);
                }
            }
        }
    }
}

// ---------------- SpMM: dst = A_norm @ src, dense [NN,512] bf16 ----------------
#define ACC8(u, vv)                              \
    a0 += (vv) * blo(u.x); a1 += (vv) * bhi(u.x); \
    a2 += (vv) * blo(u.y); a3 += (vv) * bhi(u.y); \
    a4 += (vv) * blo(u.z); a5 += (vv) * bhi(u.z); \
    a6 += (vv) * blo(u.w); a7 += (vv) * bhi(u.w);

__global__ __launch_bounds__(256) void spmm_kernel(
    const unsigned short* __restrict__ src, unsigned short* __restrict__ dst,
    const int* __restrict__ rp2, const int* __restrict__ cols,
    const float* __restrict__ dinv) {
    int i = blockIdx.x * 4 + (threadIdx.x >> 6);
    if (i >= NN) return;
    int lane = threadIdx.x & 63;
    const float di = dinv[i];
    const unsigned short* bin = src + lane * 8;

    float a0, a1, a2, a3, a4, a5, a6, a7;
    {   // self-loop
        uint4 u = *(const uint4*)(bin + (size_t)i * FI);
        float s = di * di;
        a0 = s * blo(u.x); a1 = s * bhi(u.x);
        a2 = s * blo(u.y); a3 = s * bhi(u.y);
        a4 = s * blo(u.z); a5 = s * bhi(u.z);
        a6 = s * blo(u.w); a7 = s * bhi(u.w);
    }
    int k = rp2[i * NB], e = rp2[i * NB + NB];
    for (; k + 8 <= e; k += 8) {
        int c0 = cols[k + 0], c1 = cols[k + 1], c2 = cols[k + 2], c3 = cols[k + 3];
        int c4 = cols[k + 4], c5 = cols[k + 5], c6 = cols[k + 6], c7 = cols[k + 7];
        float w0 = dinv[c0], w1 = dinv[c1], w2 = dinv[c2], w3 = dinv[c3];
        float w4 = dinv[c4], w5 = dinv[c5], w6 = dinv[c6], w7 = dinv[c7];
        uint4 u0 = *(const uint4*)(bin + (size_t)c0 * FI);
        uint4 u1 = *(const uint4*)(bin + (size_t)c1 * FI);
        uint4 u2 = *(const uint4*)(bin + (size_t)c2 * FI);
        uint4 u3 = *(const uint4*)(bin + (size_t)c3 * FI);
        uint4 u4 = *(const uint4*)(bin + (size_t)c4 * FI);
        uint4 u5 = *(const uint4*)(bin + (size_t)c5 * FI);
        uint4 u6 = *(const uint4*)(bin + (size_t)c6 * FI);
        uint4 u7 = *(const uint4*)(bin + (size_t)c7 * FI);
        float v0 = di * w0, v1 = di * w1, v2 = di * w2, v3 = di * w3;
        float v4 = di * w4, v5 = di * w5, v6 = di * w6, v7 = di * w7;
        ACC8(u0, v0) ACC8(u1, v1) ACC8(u2, v2) ACC8(u3, v3)
        ACC8(u4, v4) ACC8(u5, v5) ACC8(u6, v6) ACC8(u7, v7)
    }
    for (; k < e; ++k) {
        int cc = cols[k];
        float v = di * dinv[cc];
        uint4 u = *(const uint4*)(bin + (size_t)cc * FI);
        ACC8(u, v)
    }
    uint4 o;
    o.x = ((unsigned int)f2b(a1) << 16) | f2b(a0);
    o.y = ((unsigned int)f2b(a3) << 16) | f2b(a2);
    o.z = ((unsigned int)f2b(a5) << 16) | f2b(a4);
    o.w = ((unsigned int)f2b(a7) << 16) | f2b(a6);
    *(uint4*)(dst + lane * 8 + (size_t)i * FI) = o;
}

// ---------------- GEMM2 + log_softmax (fp32 output), 3 dense A-segments ----------------
__global__ __launch_bounds__(256) void gemm2_kernel(
    const unsigned short* __restrict__ tb, const unsigned short* __restrict__ s1b,
    const unsigned short* __restrict__ s2b, const unsigned short* __restrict__ wct,
    const float* __restrict__ b2p, float* __restrict__ out) {
    int wave = threadIdx.x >> 6, lane = threadIdx.x & 63;
    int q = lane >> 4, c = lane & 15;
    int row0 = blockIdx.x * 64 + wave * 16;
    int ra = row0 + c; ra = ra < NN ? ra : NN - 1;
    const unsigned short* seg[3] = { tb + (size_t)ra * FI + q * 8,
                                     s1b + (size_t)ra * FI + q * 8,
                                     s2b + (size_t)ra * FI + q * 8 };
    const unsigned short* bp0 = wct + (size_t)(c)      * HW + q * 8;
    const unsigned short* bp1 = wct + (size_t)(16 + c) * HW + q * 8;
    const unsigned short* bp2 = wct + (size_t)(32 + c) * HW + q * 8;

    float4v A0 = {0.f,0.f,0.f,0.f}, A1 = {0.f,0.f,0.f,0.f}, A2 = {0.f,0.f,0.f,0.f};
    #pragma unroll
    for (int s = 0; s < 3; ++s) {
        const unsigned short* ap = seg[s];
        #pragma unroll 4
        for (int k0 = 0; k0 < 512; k0 += 32) {
            short8 a  = *(const short8*)(ap + k0);
            short8 b0 = *(const short8*)(bp0 + s * 512 + k0);
            short8 b1 = *(const short8*)(bp1 + s * 512 + k0);
            short8 b2 = *(const short8*)(bp2 + s * 512 + k0);
            A0 = __builtin_amdgcn_mfma_f32_16x16x32_bf16(a, b0, A0, 0, 0, 0);
            A1 = __builtin_amdgcn_mfma_f32_16x16x32_bf16(a, b1, A1, 0, 0, 0);
            A2 = __builtin_amdgcn_mfma_f32_16x16x32_bf16(a, b2, A2, 0, 0, 0);
        }
    }
    float bias0 = b2p[c];
    float bias1 = b2p[16 + c];
    float bias2 = (c < 8) ? b2p[32 + c] : 0.f;
    #pragma unroll
    for (int r = 0; r < 4; ++r) {
        float v0 = A0[r] + bias0;
        float v1 = A1[r] + bias1;
        float v2 = (c < 8) ? (A2[r] + bias2) : -1e30f;
        float mx = fmaxf(fmaxf(v0, v1), v2);
        #pragma unroll
        for (int d = 1; d < 16; d <<= 1) mx = fmaxf(mx, __shfl_xor(mx, d, 64));
        float s = __expf(v0 - mx) + __expf(v1 - mx) + ((c < 8) ? __expf(v2 - mx) : 0.f);
        #pragma unroll
        for (int d = 1; d < 16; d <<= 1) s += __shfl_xor(s, d, 64);
        float lse = mx + __logf(s);
        int rowg = row0 + q * 4 + r;
        if (rowg < NN) {
            out[(size_t)rowg * NC + c]      = v0 - lse;
            out[(size_t)rowg * NC + 16 + c] = v1 - lse;
            if (c < 8) out[(size_t)rowg * NC + 32 + c] = v2 - lse;
        }
    }
}

extern "C" void kernel_launch(void* const* d_in, const int* in_sizes, int n_in,
                              void* d_out, int out_size, void* d_ws, size_t ws_size,
                              hipStream_t stream) {
    const float* x  = (const float*)d_in[0];
    const int*   er = (const int*)d_in[1];
    const int*   ec = (const int*)d_in[2];
    const float* W1 = (const float*)d_in[3];
    const float* b1 = (const float*)d_in[4];
    const float* W2 = (const float*)d_in[5];
    const float* b2 = (const float*)d_in[6];
    float* out = (float*)d_out;

    char* p = (char*)d_ws;
    auto alloc = [&](size_t bytes) { char* r = p; p += (bytes + 255) & ~((size_t)255); return r; };
    int*   cnt2   = (int*)  alloc((size_t)NBN * 4);
    int*   deg    = (int*)  alloc((size_t)NN * 4);
    int*   rp2    = (int*)  alloc((size_t)(NBN + 1) * 4);
    float* dinv   = (float*)alloc((size_t)NN * 4);
    int*   bsum   = (int*)  alloc((size_t)SCAN_NBLK * 4);
    int*   boff   = (int*)  alloc((size_t)SCAN_NBLK * 4);
    int*   rank   = (int*)  alloc((size_t)NE * 4);
    int*   colss  = (int*)  alloc((size_t)NE * 4);
    unsigned short* w1t  = (unsigned short*)alloc((size_t)512 * 512 * 2);
    unsigned short* wct  = (unsigned short*)alloc((size_t)48 * HW * 2);
    unsigned short* xb   = (unsigned short*)alloc((size_t)NN * FI * 2);
    unsigned short* tbuf = (unsigned short*)alloc((size_t)NN * FI * 2);
    unsigned short* s1b  = (unsigned short*)alloc((size_t)NN * FI * 2);
    unsigned short* s2b  = xb;   // xb dead after gemm1; reuse for s2

    hipMemsetAsync(cnt2, 0, (size_t)NBN * 4, stream);
    hipMemsetAsync(deg, 0, (size_t)NN * 4, stream);

    convx_kernel<<<(NN * 64 + 255) / 256, 256, 0, stream>>>(x, xb);
    transpose_kernel<<<(512 * 512) / 256, 256, 0, stream>>>(W1, w1t);
    wcat_kernel<<<(48 * HW) / 256, 256, 0, stream>>>(W2, wct);

    count_kernel<<<(NE + 255) / 256, 256, 0, stream>>>(er, ec, cnt2, deg, rank);
    scan1_kernel<<<SCAN_NBLK, 1024, 0, stream>>>(cnt2, rp2, bsum);
    scan2_kernel<<<1, 1024, 0, stream>>>(bsum, boff);
    scan3_kernel<<<(NBN + 255) / 256, 256, 0, stream>>>(rp2, boff, deg, dinv);
    scatter_kernel<<<(NE + 255) / 256, 256, 0, stream>>>(er, ec, rp2, rank, colss);

    gemm1_kernel<<<dim3((NN + 127) / 128, DD / 128), 256, 0, stream>>>(xb, w1t, b1, tbuf);
    spmm_kernel<<<(NN + 3) / 4, 256, 0, stream>>>(tbuf, s1b, rp2, colss, dinv);
    spmm_kernel<<<(NN + 3) / 4, 256, 0, stream>>>(s1b, s2b, rp2, colss, dinv);
    gemm2_kernel<<<(NN + 63) / 64, 256, 0, stream>>>(tbuf, s1b, s2b, wct, b2, out);
}

// Round 7
// 767.360 us; speedup vs baseline: 1.2743x; 1.2743x over previous
//
#include <hip/hip_runtime.h>
#include <stdint.h>

#define NN 50000
#define NE 1600000
#define FI 512
#define DD 512
#define NC 40
#define HW 1536
#define SCAN_NB 49  // ceil(NN/1024)

typedef __attribute__((ext_vector_type(8))) short short8;
typedef __attribute__((ext_vector_type(4))) float float4v;
typedef __attribute__((ext_vector_type(2))) float f32x2;

static __device__ __forceinline__ unsigned short f2b(float f) {
    union { float f; unsigned int i; } v; v.f = f;
    unsigned int r = v.i + 0x7fffu + ((v.i >> 16) & 1u);
    return (unsigned short)(r >> 16);
}
static __device__ __forceinline__ float blo(unsigned int u) {
    union { unsigned int i; float f; } v; v.i = u << 16; return v.f;
}
static __device__ __forceinline__ float bhi(unsigned int u) {
    union { unsigned int i; float f; } v; v.i = u & 0xffff0000u; return v.f;
}
static __device__ __forceinline__ unsigned char f2e4m3(float f) {
    return (unsigned char)(__builtin_amdgcn_cvt_pk_fp8_f32(f, f, 0, false) & 0xFF);
}
static __device__ __forceinline__ void async_copy16(void* lds, const void* g) {
    __builtin_amdgcn_global_load_lds((const __attribute__((address_space(1))) void*)g,
                                     (__attribute__((address_space(3))) void*)lds, 16, 0, 0);
}

// ---------------- x (fp32) -> bf16 dense [NN,512] ----------------
__global__ void convx_kernel(const float* __restrict__ x, unsigned short* __restrict__ dst) {
    int t = blockIdx.x * 256 + threadIdx.x;
    if (t >= NN * 64) return;
    const float* xf = x + (size_t)t * 8;
    float4 v0 = *(const float4*)(xf);
    float4 v1 = *(const float4*)(xf + 4);
    uint4 u;
    u.x = ((unsigned)f2b(v0.y) << 16) | f2b(v0.x);
    u.y = ((unsigned)f2b(v0.w) << 16) | f2b(v0.z);
    u.z = ((unsigned)f2b(v1.y) << 16) | f2b(v1.x);
    u.w = ((unsigned)f2b(v1.w) << 16) | f2b(v1.z);
    *(uint4*)(dst + (size_t)t * 8) = u;
}

// ---------------- CSR build (plain rows; rank for atomic-free scatter) ----------------
__global__ void count_kernel(const int* __restrict__ row, const int* __restrict__ col,
                             int* cnt_row, int* deg, int* __restrict__ rank) {
    int e = blockIdx.x * 256 + threadIdx.x;
    if (e < NE) {
        rank[e] = atomicAdd(&cnt_row[row[e]], 1);
        atomicAdd(&deg[col[e]], 1);
    }
}

__global__ __launch_bounds__(1024) void scan1_kernel(const int* __restrict__ cnt,
                                                     int* __restrict__ excl, int* __restrict__ bsum) {
    __shared__ int buf[1024];
    int tid = threadIdx.x, gid = blockIdx.x * 1024 + tid;
    int v = (gid < NN) ? cnt[gid] : 0;
    buf[tid] = v;
    __syncthreads();
    int acc = v;
    for (int off = 1; off < 1024; off <<= 1) {
        int t = (tid >= off) ? buf[tid - off] : 0;
        __syncthreads();
        acc += t;
        buf[tid] = acc;
        __syncthreads();
    }
    if (gid < NN) excl[gid] = acc - v;
    if (tid == 1023) bsum[blockIdx.x] = acc;
}

__global__ void scan2_kernel(const int* __restrict__ bsum, int* __restrict__ boff) {
    int tid = threadIdx.x;  // one wave, SCAN_NB=49
    int orig = (tid < SCAN_NB) ? bsum[tid] : 0;
    int v = orig;
    #pragma unroll
    for (int off = 1; off < 64; off <<= 1) {
        int t = __shfl_up(v, off, 64);
        if (tid >= off) v += t;
    }
    if (tid < SCAN_NB) boff[tid] = v - orig;
}

__global__ void scan3_kernel(int* __restrict__ rowptr, const int* __restrict__ boff,
                             const int* __restrict__ deg, float* __restrict__ dinv) {
    int gid = blockIdx.x * 256 + threadIdx.x;
    if (gid < NN) {
        rowptr[gid] += boff[gid >> 10];
        dinv[gid] = rsqrtf((float)(deg[gid] + 1));
    }
    if (gid == 0) rowptr[NN] = NE;
}

__global__ void scatter_kernel(const int* __restrict__ row, const int* __restrict__ col,
                               const int* __restrict__ rowptr, const int* __restrict__ rank,
                               int* __restrict__ cols_out) {
    int e = blockIdx.x * 256 + threadIdx.x;
    if (e < NE) cols_out[rowptr[row[e]] + rank[e]] = col[e];
}

// ---------------- weight prep ----------------
__global__ void transpose_kernel(const float* __restrict__ w, unsigned short* __restrict__ wt) {
    int t = blockIdx.x * 256 + threadIdx.x;   // 512*512
    int n = t & 511, k = t >> 9;
    wt[n * 512 + k] = f2b(w[(size_t)k * 512 + n]);
}

__global__ void wcat_kernel(const float* __restrict__ w2, unsigned short* __restrict__ wct) {
    int t = blockIdx.x * 256 + threadIdx.x;   // 48*1536
    int k = t % HW, n = t / HW;
    float v = 0.f;
    if (n < NC) {
        if (k < 512)       v = w2[(size_t)k * NC + n] + w2[(size_t)(k + 512) * NC + n];
        else if (k < 1024) v = w2[(size_t)(k + 512) * NC + n] + w2[(size_t)(k + 1024) * NC + n];
        else               v = w2[(size_t)(k + 1024) * NC + n];
    }
    wct[n * HW + k] = f2b(v);
}

// ---------------- GEMM1: t = relu(x@W1 + b1) -> tbuf (bf16) + t8 (fp8) ----------------
__global__ __launch_bounds__(256) void gemm1_kernel(
    const unsigned short* __restrict__ xb, const unsigned short* __restrict__ w1t,
    const float* __restrict__ b1, unsigned short* __restrict__ tbuf,
    unsigned char* __restrict__ t8) {
    __shared__ __align__(16) unsigned short As[128 * 32];
    __shared__ __align__(16) unsigned short Bs[128 * 32];
    const int tid = threadIdx.x;
    const int wave = tid >> 6, lane = tid & 63;
    const int q = lane >> 4, c = lane & 15;
    const int wm = wave & 1, wn = wave >> 1;
    const int m0 = blockIdx.x * 128, n0 = blockIdx.y * 128;

    float4v acc[4][4];
    for (int i = 0; i < 4; ++i)
        for (int j = 0; j < 4; ++j)
            acc[i][j] = (float4v){0.f, 0.f, 0.f, 0.f};

    for (int k0 = 0; k0 < FI; k0 += 32) {
        __syncthreads();
        #pragma unroll
        for (int h = 0; h < 2; ++h) {
            int chunk = h * 256 + wave * 64 + lane;
            int r = chunk >> 2, kc = chunk & 3;
            int gm = m0 + r; gm = gm < NN ? gm : NN - 1;
            async_copy16((char*)As + (size_t)(h * 256 + wave * 64) * 16,
                         xb + (size_t)gm * FI + k0 + kc * 8);
            async_copy16((char*)Bs + (size_t)(h * 256 + wave * 64) * 16,
                         w1t + (size_t)(n0 + r) * FI + k0 + kc * 8);
        }
        __syncthreads();
        short8 a[4], b[4];
        #pragma unroll
        for (int mi = 0; mi < 4; ++mi)
            a[mi] = *(const short8*)(As + ((wm * 64 + mi * 16 + c) * 32 + q * 8));
        #pragma unroll
        for (int ni = 0; ni < 4; ++ni)
            b[ni] = *(const short8*)(Bs + ((wn * 64 + ni * 16 + c) * 32 + q * 8));
        #pragma unroll
        for (int mi = 0; mi < 4; ++mi)
            #pragma unroll
            for (int ni = 0; ni < 4; ++ni)
                acc[mi][ni] = __builtin_amdgcn_mfma_f32_16x16x32_bf16(a[mi], b[ni], acc[mi][ni], 0, 0, 0);
    }
    #pragma unroll
    for (int ni = 0; ni < 4; ++ni) {
        int col = n0 + wn * 64 + ni * 16 + c;
        float bias = b1[col];
        #pragma unroll
        for (int mi = 0; mi < 4; ++mi) {
            int rbase = m0 + wm * 64 + mi * 16 + q * 4;
            #pragma unroll
            for (int r = 0; r < 4; ++r) {
                int row = rbase + r;
                if (row < NN) {
                    float v = acc[mi][ni][r] + bias;
                    v = v > 0.f ? v : 0.f;
                    tbuf[(size_t)row * FI + col] = f2b(v);
                    t8[(size_t)row * FI + col] = f2e4m3(v);
                }
            }
        }
    }
}

// ---------------- SpMM (fp8 gather): dstb = A_norm @ src ----------------
// src8: fp8 copy of src [NN,512]; srcb: bf16 src (self-loop read); dst8 optional fp8 out.
#define DEC8(g, vv)                                                        \
    {   f32x2 p0 = __builtin_amdgcn_cvt_pk_f32_fp8((int)(g).x, false);      \
        f32x2 p1 = __builtin_amdgcn_cvt_pk_f32_fp8((int)(g).x, true);       \
        f32x2 p2 = __builtin_amdgcn_cvt_pk_f32_fp8((int)(g).y, false);      \
        f32x2 p3 = __builtin_amdgcn_cvt_pk_f32_fp8((int)(g).y, true);       \
        a0 += (vv) * p0.x; a1 += (vv) * p0.y;                               \
        a2 += (vv) * p1.x; a3 += (vv) * p1.y;                               \
        a4 += (vv) * p2.x; a5 += (vv) * p2.y;                               \
        a6 += (vv) * p3.x; a7 += (vv) * p3.y; }

__global__ __launch_bounds__(256) void spmm_kernel(
    const unsigned char* __restrict__ src8, const unsigned short* __restrict__ srcb,
    unsigned short* __restrict__ dstb, unsigned char* __restrict__ dst8,
    const int* __restrict__ rowptr, const int* __restrict__ cols,
    const float* __restrict__ dinv, int write8) {
    int i = blockIdx.x * 4 + (threadIdx.x >> 6);
    if (i >= NN) return;
    int lane = threadIdx.x & 63;
    const float di = dinv[i];
    const unsigned char* bin = src8 + lane * 8;

    float a0, a1, a2, a3, a4, a5, a6, a7;
    {   // self-loop from the bf16 copy (unit-stride, cheap, better precision)
        uint4 u = *(const uint4*)(srcb + (size_t)i * FI + lane * 8);
        float s = di * di;
        a0 = s * blo(u.x); a1 = s * bhi(u.x);
        a2 = s * blo(u.y); a3 = s * bhi(u.y);
        a4 = s * blo(u.z); a5 = s * bhi(u.z);
        a6 = s * blo(u.w); a7 = s * bhi(u.w);
    }
    int k = rowptr[i], e = rowptr[i + 1];
    for (; k + 8 <= e; k += 8) {
        int c0 = cols[k + 0], c1 = cols[k + 1], c2 = cols[k + 2], c3 = cols[k + 3];
        int c4 = cols[k + 4], c5 = cols[k + 5], c6 = cols[k + 6], c7 = cols[k + 7];
        float w0 = dinv[c0], w1 = dinv[c1], w2 = dinv[c2], w3 = dinv[c3];
        float w4 = dinv[c4], w5 = dinv[c5], w6 = dinv[c6], w7 = dinv[c7];
        uint2 g0 = *(const uint2*)(bin + (size_t)c0 * FI);
        uint2 g1 = *(const uint2*)(bin + (size_t)c1 * FI);
        uint2 g2 = *(const uint2*)(bin + (size_t)c2 * FI);
        uint2 g3 = *(const uint2*)(bin + (size_t)c3 * FI);
        uint2 g4 = *(const uint2*)(bin + (size_t)c4 * FI);
        uint2 g5 = *(const uint2*)(bin + (size_t)c5 * FI);
        uint2 g6 = *(const uint2*)(bin + (size_t)c6 * FI);
        uint2 g7 = *(const uint2*)(bin + (size_t)c7 * FI);
        float v0 = di * w0, v1 = di * w1, v2 = di * w2, v3 = di * w3;
        float v4 = di * w4, v5 = di * w5, v6 = di * w6, v7 = di * w7;
        DEC8(g0, v0) DEC8(g1, v1) DEC8(g2, v2) DEC8(g3, v3)
        DEC8(g4, v4) DEC8(g5, v5) DEC8(g6, v6) DEC8(g7, v7)
    }
    for (; k < e; ++k) {
        int cc = cols[k];
        float v = di * dinv[cc];
        uint2 g = *(const uint2*)(bin + (size_t)cc * FI);
        DEC8(g, v)
    }
    uint4 o;
    o.x = ((unsigned int)f2b(a1) << 16) | f2b(a0);
    o.y = ((unsigned int)f2b(a3) << 16) | f2b(a2);
    o.z = ((unsigned int)f2b(a5) << 16) | f2b(a4);
    o.w = ((unsigned int)f2b(a7) << 16) | f2b(a6);
    *(uint4*)(dstb + lane * 8 + (size_t)i * FI) = o;
    if (write8) {
        unsigned r0 = (unsigned)__builtin_amdgcn_cvt_pk_fp8_f32(a0, a1, 0, false);
        r0 = (unsigned)__builtin_amdgcn_cvt_pk_fp8_f32(a2, a3, (int)r0, true);
        unsigned r1 = (unsigned)__builtin_amdgcn_cvt_pk_fp8_f32(a4, a5, 0, false);
        r1 = (unsigned)__builtin_amdgcn_cvt_pk_fp8_f32(a6, a7, (int)r1, true);
        uint2 o8; o8.x = r0; o8.y = r1;
        *(uint2*)(dst8 + lane * 8 + (size_t)i * FI) = o8;
    }
}

// ---------------- GEMM2 + log_softmax (fp32 output), 3 dense A-segments ----------------
__global__ __launch_bounds__(256) void gemm2_kernel(
    const unsigned short* __restrict__ tb, const unsigned short* __restrict__ s1b,
    const unsigned short* __restrict__ s2b, const unsigned short* __restrict__ wct,
    const float* __restrict__ b2p, float* __restrict__ out) {
    int wave = threadIdx.x >> 6, lane = threadIdx.x & 63;
    int q = lane >> 4, c = lane & 15;
    int row0 = blockIdx.x * 64 + wave * 16;
    int ra = row0 + c; ra = ra < NN ? ra : NN - 1;
    const unsigned short* seg[3] = { tb + (size_t)ra * FI + q * 8,
                                     s1b + (size_t)ra * FI + q * 8,
                                     s2b + (size_t)ra * FI + q * 8 };
    const unsigned short* bp0 = wct + (size_t)(c)      * HW + q * 8;
    const unsigned short* bp1 = wct + (size_t)(16 + c) * HW + q * 8;
    const unsigned short* bp2 = wct + (size_t)(32 + c) * HW + q * 8;

    float4v A0 = {0.f,0.f,0.f,0.f}, A1 = {0.f,0.f,0.f,0.f}, A2 = {0.f,0.f,0.f,0.f};
    #pragma unroll
    for (int s = 0; s < 3; ++s) {
        const unsigned short* ap = seg[s];
        #pragma unroll 4
        for (int k0 = 0; k0 < 512; k0 += 32) {
            short8 a  = *(const short8*)(ap + k0);
            short8 b0 = *(const short8*)(bp0 + s * 512 + k0);
            short8 b1 = *(const short8*)(bp1 + s * 512 + k0);
            short8 b2 = *(const short8*)(bp2 + s * 512 + k0);
            A0 = __builtin_amdgcn_mfma_f32_16x16x32_bf16(a, b0, A0, 0, 0, 0);
            A1 = __builtin_amdgcn_mfma_f32_16x16x32_bf16(a, b1, A1, 0, 0, 0);
            A2 = __builtin_amdgcn_mfma_f32_16x16x32_bf16(a, b2, A2, 0, 0, 0);
        }
    }
    float bias0 = b2p[c];
    float bias1 = b2p[16 + c];
    float bias2 = (c < 8) ? b2p[32 + c] : 0.f;
    #pragma unroll
    for (int r = 0; r < 4; ++r) {
        float v0 = A0[r] + bias0;
        float v1 = A1[r] + bias1;
        float v2 = (c < 8) ? (A2[r] + bias2) : -1e30f;
        float mx = fmaxf(fmaxf(v0, v1), v2);
        #pragma unroll
        for (int d = 1; d < 16; d <<= 1) mx = fmaxf(mx, __shfl_xor(mx, d, 64));
        float s = __expf(v0 - mx) + __expf(v1 - mx) + ((c < 8) ? __expf(v2 - mx) : 0.f);
        #pragma unroll
        for (int d = 1; d < 16; d <<= 1) s += __shfl_xor(s, d, 64);
        float lse = mx + __logf(s);
        int rowg = row0 + q * 4 + r;
        if (rowg < NN) {
            out[(size_t)rowg * NC + c]      = v0 - lse;
            out[(size_t)rowg * NC + 16 + c] = v1 - lse;
            if (c < 8) out[(size_t)rowg * NC + 32 + c] = v2 - lse;
        }
    }
}

extern "C" void kernel_launch(void* const* d_in, const int* in_sizes, int n_in,
                              void* d_out, int out_size, void* d_ws, size_t ws_size,
                              hipStream_t stream) {
    const float* x  = (const float*)d_in[0];
    const int*   er = (const int*)d_in[1];
    const int*   ec = (const int*)d_in[2];
    const float* W1 = (const float*)d_in[3];
    const float* b1 = (const float*)d_in[4];
    const float* W2 = (const float*)d_in[5];
    const float* b2 = (const float*)d_in[6];
    float* out = (float*)d_out;

    char* p = (char*)d_ws;
    auto alloc = [&](size_t bytes) { char* r = p; p += (bytes + 255) & ~((size_t)255); return r; };
    int*   cnt_row = (int*)  alloc((size_t)NN * 4);
    int*   deg     = (int*)  alloc((size_t)NN * 4);
    int*   rowptr  = (int*)  alloc((size_t)(NN + 1) * 4);
    float* dinv    = (float*)alloc((size_t)NN * 4);
    int*   bsum    = (int*)  alloc((size_t)SCAN_NB * 4);
    int*   boff    = (int*)  alloc((size_t)SCAN_NB * 4);
    int*   rank    = (int*)  alloc((size_t)NE * 4);
    int*   colss   = (int*)  alloc((size_t)NE * 4);
    unsigned short* w1t  = (unsigned short*)alloc((size_t)512 * 512 * 2);
    unsigned short* wct  = (unsigned short*)alloc((size_t)48 * HW * 2);
    unsigned short* xb   = (unsigned short*)alloc((size_t)NN * FI * 2);
    unsigned short* tbuf = (unsigned short*)alloc((size_t)NN * FI * 2);
    unsigned short* s1b  = (unsigned short*)alloc((size_t)NN * FI * 2);
    unsigned char*  t8   = (unsigned char*)alloc((size_t)NN * FI);
    unsigned char*  s18  = (unsigned char*)alloc((size_t)NN * FI);
    unsigned short* s2b  = xb;   // xb dead after gemm1; reuse for s2

    hipMemsetAsync(cnt_row, 0, (size_t)NN * 4, stream);
    hipMemsetAsync(deg, 0, (size_t)NN * 4, stream);

    convx_kernel<<<(NN * 64 + 255) / 256, 256, 0, stream>>>(x, xb);
    transpose_kernel<<<(512 * 512) / 256, 256, 0, stream>>>(W1, w1t);
    wcat_kernel<<<(48 * HW) / 256, 256, 0, stream>>>(W2, wct);

    count_kernel<<<(NE + 255) / 256, 256, 0, stream>>>(er, ec, cnt_row, deg, rank);
    scan1_kernel<<<SCAN_NB, 1024, 0, stream>>>(cnt_row, rowptr, bsum);
    scan2_kernel<<<1, 64, 0, stream>>>(bsum, boff);
    scan3_kernel<<<(NN + 255) / 256, 256, 0, stream>>>(rowptr, boff, deg, dinv);
    scatter_kernel<<<(NE + 255) / 256, 256, 0, stream>>>(er, ec, rowptr, rank, colss);

    gemm1_kernel<<<dim3((NN + 127) / 128, DD / 128), 256, 0, stream>>>(xb, w1t, b1, tbuf, t8);
    spmm_kernel<<<(NN + 3) / 4, 256, 0, stream>>>(t8, tbuf, s1b, s18, rowptr, colss, dinv, 1);
    spmm_kernel<<<(NN + 3) / 4, 256, 0, stream>>>(s18, s1b, s2b, (unsigned char*)nullptr, rowptr, colss, dinv, 0);
    gemm2_kernel<<<(NN + 63) / 64, 256, 0, stream>>>(tbuf, s1b, s2b, wct, b2, out);
}

// Round 8
// 635.371 us; speedup vs baseline: 1.5390x; 1.2077x over previous
//
#include <hip/hip_runtime.h>
#include <stdint.h>

#define NN 50000
#define NE 1600000
#define FI 512
#define DD 512
#define NC 40
#define HW 1536
#define SCAN_NB 49        // ceil(NN/1024)
#define CB 256            // histogram blocks
#define EPB (NE / CB)     // 6250 edges per histogram block
#define HWRD 12500        // 50000 bins / 4 bytes per word

typedef __attribute__((ext_vector_type(8))) short short8;
typedef __attribute__((ext_vector_type(4))) float float4v;
typedef __attribute__((ext_vector_type(2))) float f32x2;

static __device__ __forceinline__ unsigned short f2b(float f) {
    union { float f; unsigned int i; } v; v.f = f;
    unsigned int r = v.i + 0x7fffu + ((v.i >> 16) & 1u);
    return (unsigned short)(r >> 16);
}
static __device__ __forceinline__ float blo(unsigned int u) {
    union { unsigned int i; float f; } v; v.i = u << 16; return v.f;
}
static __device__ __forceinline__ float bhi(unsigned int u) {
    union { unsigned int i; float f; } v; v.i = u & 0xffff0000u; return v.f;
}
static __device__ __forceinline__ unsigned char f2e4m3(float f) {
    return (unsigned char)(__builtin_amdgcn_cvt_pk_fp8_f32(f, f, 0, false) & 0xFF);
}
static __device__ __forceinline__ void async_copy16(void* lds, const void* g) {
    __builtin_amdgcn_global_load_lds((const __attribute__((address_space(1))) void*)g,
                                     (__attribute__((address_space(3))) void*)lds, 16, 0, 0);
}

// ================= MEGA1: [count_row | count_col | convx | transpose | wcat] =================
// blocks [0,CB): row histogram + local rank; [CB,2CB): col histogram;
// then 12500 convx blocks, 1024 transpose blocks, 288 wcat blocks.
__global__ __launch_bounds__(256) void mega1_kernel(
    const int* __restrict__ er, const int* __restrict__ ec,
    const float* __restrict__ x, const float* __restrict__ W1, const float* __restrict__ W2,
    unsigned char* __restrict__ rank, unsigned* __restrict__ hist_row, unsigned* __restrict__ hist_col,
    unsigned short* __restrict__ xb, unsigned short* __restrict__ w1t, unsigned short* __restrict__ wct) {
    __shared__ unsigned hb[HWRD];
    int bid = blockIdx.x, tid = threadIdx.x;
    if (bid < 2 * CB) {
        for (int w = tid; w < HWRD; w += 256) hb[w] = 0;
        __syncthreads();
        int b = bid & (CB - 1);
        int e0 = b * EPB;
        if (bid < CB) {   // row histogram + rank
            for (int e = e0 + tid; e < e0 + EPB; e += 256) {
                int r = er[e];
                unsigned sh = (r & 3) * 8;
                unsigned old = atomicAdd(&hb[r >> 2], 1u << sh);
                rank[e] = (unsigned char)((old >> sh) & 0xFFu);
            }
        } else {          // col histogram (in-degree)
            for (int e = e0 + tid; e < e0 + EPB; e += 256) {
                int c = ec[e];
                atomicAdd(&hb[c >> 2], 1u << ((c & 3) * 8));
            }
        }
        __syncthreads();
        unsigned* dst = (bid < CB ? hist_row : hist_col) + (size_t)b * HWRD;
        for (int w = tid; w < HWRD; w += 256) dst[w] = hb[w];
        return;
    }
    bid -= 2 * CB;
    if (bid < 12500) {    // convx: fp32 -> bf16, 8 elems/thread
        int t = bid * 256 + tid;
        const float* xf = x + (size_t)t * 8;
        float4 v0 = *(const float4*)(xf);
        float4 v1 = *(const float4*)(xf + 4);
        uint4 u;
        u.x = ((unsigned)f2b(v0.y) << 16) | f2b(v0.x);
        u.y = ((unsigned)f2b(v0.w) << 16) | f2b(v0.z);
        u.z = ((unsigned)f2b(v1.y) << 16) | f2b(v1.x);
        u.w = ((unsigned)f2b(v1.w) << 16) | f2b(v1.z);
        *(uint4*)(xb + (size_t)t * 8) = u;
        return;
    }
    bid -= 12500;
    if (bid < 1024) {     // transpose W1 -> bf16 w1t[n][k]
        int t = bid * 256 + tid;
        int n = t & 511, k = t >> 9;
        w1t[n * 512 + k] = f2b(W1[(size_t)k * 512 + n]);
        return;
    }
    bid -= 1024;
    {                     // wcat: combined final weight, transposed, bf16 (48*1536)
        int t = bid * 256 + tid;
        if (t < 48 * HW) {
            int k = t % HW, n = t / HW;
            float v = 0.f;
            if (n < NC) {
                if (k < 512)       v = W2[(size_t)k * NC + n] + W2[(size_t)(k + 512) * NC + n];
                else if (k < 1024) v = W2[(size_t)(k + 512) * NC + n] + W2[(size_t)(k + 1024) * NC + n];
                else               v = W2[(size_t)(k + 1024) * NC + n];
            }
            wct[n * HW + k] = f2b(v);
        }
    }
}

// ================= PREP: SWAR prefix over blocks (rows) + reduce (cols) =================
__global__ __launch_bounds__(256) void prep_kernel(
    const unsigned* __restrict__ hist_row, const unsigned* __restrict__ hist_col,
    unsigned* __restrict__ base_words, int* __restrict__ cntI, int* __restrict__ degI) {
    int t = blockIdx.x * 256 + threadIdx.x;
    if (t < HWRD) {
        unsigned acc = 0;   // 4 packed byte counters; totals <256/byte so no carry
        for (int b = 0; b < CB; ++b) {
            unsigned h = hist_row[(size_t)b * HWRD + t];
            base_words[(size_t)b * HWRD + t] = acc;
            acc += h;
        }
        int4 o; o.x = acc & 0xFF; o.y = (acc >> 8) & 0xFF; o.z = (acc >> 16) & 0xFF; o.w = (acc >> 24) & 0xFF;
        ((int4*)cntI)[t] = o;
    } else if (t < 2 * HWRD) {
        int w = t - HWRD;
        unsigned acc = 0;
        for (int b = 0; b < CB; ++b) acc += hist_col[(size_t)b * HWRD + w];
        int4 o; o.x = acc & 0xFF; o.y = (acc >> 8) & 0xFF; o.z = (acc >> 16) & 0xFF; o.w = (acc >> 24) & 0xFF;
        ((int4*)degI)[w] = o;
    }
}

// ================= scans =================
__global__ __launch_bounds__(1024) void scan1_kernel(const int* __restrict__ cnt,
                                                     int* __restrict__ excl, int* __restrict__ bsum) {
    __shared__ int buf[1024];
    int tid = threadIdx.x, gid = blockIdx.x * 1024 + tid;
    int v = (gid < NN) ? cnt[gid] : 0;
    buf[tid] = v;
    __syncthreads();
    int acc = v;
    for (int off = 1; off < 1024; off <<= 1) {
        int t = (tid >= off) ? buf[tid - off] : 0;
        __syncthreads();
        acc += t;
        buf[tid] = acc;
        __syncthreads();
    }
    if (gid < NN) excl[gid] = acc - v;
    if (tid == 1023) bsum[blockIdx.x] = acc;
}

__global__ void scan2_kernel(const int* __restrict__ bsum, int* __restrict__ boff) {
    int tid = threadIdx.x;  // one wave, SCAN_NB=49
    int orig = (tid < SCAN_NB) ? bsum[tid] : 0;
    int v = orig;
    #pragma unroll
    for (int off = 1; off < 64; off <<= 1) {
        int t = __shfl_up(v, off, 64);
        if (tid >= off) v += t;
    }
    if (tid < SCAN_NB) boff[tid] = v - orig;
}

__global__ void scan3_kernel(int* __restrict__ rowptr, const int* __restrict__ boff,
                             const int* __restrict__ deg, float* __restrict__ dinv) {
    int gid = blockIdx.x * 256 + threadIdx.x;
    if (gid < NN) {
        rowptr[gid] += boff[gid >> 10];
        dinv[gid] = rsqrtf((float)(deg[gid] + 1));
    }
    if (gid == 0) rowptr[NN] = NE;
}

// ================= MEGA2: [scatter | gemm1] =================
__global__ __launch_bounds__(256) void mega2_kernel(
    const int* __restrict__ er, const int* __restrict__ ec, const int* __restrict__ rowptr,
    const unsigned char* __restrict__ rank, const unsigned char* __restrict__ base8,
    int* __restrict__ colss,
    const unsigned short* __restrict__ xb, const unsigned short* __restrict__ w1t,
    const float* __restrict__ b1, unsigned short* __restrict__ tbuf, unsigned char* __restrict__ t8) {
    __shared__ __align__(16) unsigned short As[128 * 32];
    __shared__ __align__(16) unsigned short Bs[128 * 32];
    int bid = blockIdx.x;
    if (bid < NE / 256) {   // scatter (atomic-free)
        int e = bid * 256 + threadIdx.x;
        int r = er[e], c = ec[e];
        int b = e / EPB;
        colss[rowptr[r] + (int)base8[(size_t)b * 50000 + r] + (int)rank[e]] = c;
        return;
    }
    bid -= NE / 256;
    // ---- gemm1: t = relu(x@W1+b1) -> tbuf bf16 + t8 fp8 ----
    const int m0 = (bid >> 2) * 128, n0 = (bid & 3) * 128;
    const int tid = threadIdx.x;
    const int wave = tid >> 6, lane = tid & 63;
    const int q = lane >> 4, c = lane & 15;
    const int wm = wave & 1, wn = wave >> 1;

    float4v acc[4][4];
    for (int i = 0; i < 4; ++i)
        for (int j = 0; j < 4; ++j)
            acc[i][j] = (float4v){0.f, 0.f, 0.f, 0.f};

    for (int k0 = 0; k0 < FI; k0 += 32) {
        __syncthreads();
        #pragma unroll
        for (int h = 0; h < 2; ++h) {
            int chunk = h * 256 + wave * 64 + lane;
            int r = chunk >> 2, kc = chunk & 3;
            int gm = m0 + r; gm = gm < NN ? gm : NN - 1;
            async_copy16((char*)As + (size_t)(h * 256 + wave * 64) * 16,
                         xb + (size_t)gm * FI + k0 + kc * 8);
            async_copy16((char*)Bs + (size_t)(h * 256 + wave * 64) * 16,
                         w1t + (size_t)(n0 + r) * FI + k0 + kc * 8);
        }
        __syncthreads();
        short8 a[4], b[4];
        #pragma unroll
        for (int mi = 0; mi < 4; ++mi)
            a[mi] = *(const short8*)(As + ((wm * 64 + mi * 16 + c) * 32 + q * 8));
        #pragma unroll
        for (int ni = 0; ni < 4; ++ni)
            b[ni] = *(const short8*)(Bs + ((wn * 64 + ni * 16 + c) * 32 + q * 8));
        #pragma unroll
        for (int mi = 0; mi < 4; ++mi)
            #pragma unroll
            for (int ni = 0; ni < 4; ++ni)
                acc[mi][ni] = __builtin_amdgcn_mfma_f32_16x16x32_bf16(a[mi], b[ni], acc[mi][ni], 0, 0, 0);
    }
    #pragma unroll
    for (int ni = 0; ni < 4; ++ni) {
        int col = n0 + wn * 64 + ni * 16 + c;
        float bias = b1[col];
        #pragma unroll
        for (int mi = 0; mi < 4; ++mi) {
            int rbase = m0 + wm * 64 + mi * 16 + q * 4;
            #pragma unroll
            for (int r = 0; r < 4; ++r) {
                int row = rbase + r;
                if (row < NN) {
                    float v = acc[mi][ni][r] + bias;
                    v = v > 0.f ? v : 0.f;
                    tbuf[(size_t)row * FI + col] = f2b(v);
                    t8[(size_t)row * FI + col] = f2e4m3(v);
                }
            }
        }
    }
}

// ================= SpMM (fp8 gather) =================
#define DEC8(g, vv)                                                        \
    {   f32x2 p0 = __builtin_amdgcn_cvt_pk_f32_fp8((int)(g).x, false);      \
        f32x2 p1 = __builtin_amdgcn_cvt_pk_f32_fp8((int)(g).x, true);       \
        f32x2 p2 = __builtin_amdgcn_cvt_pk_f32_fp8((int)(g).y, false);      \
        f32x2 p3 = __builtin_amdgcn_cvt_pk_f32_fp8((int)(g).y, true);       \
        a0 += (vv) * p0.x; a1 += (vv) * p0.y;                               \
        a2 += (vv) * p1.x; a3 += (vv) * p1.y;                               \
        a4 += (vv) * p2.x; a5 += (vv) * p2.y;                               \
        a6 += (vv) * p3.x; a7 += (vv) * p3.y; }

__global__ __launch_bounds__(256) void spmm_kernel(
    const unsigned char* __restrict__ src8, const unsigned short* __restrict__ srcb,
    unsigned short* __restrict__ dstb, unsigned char* __restrict__ dst8,
    const int* __restrict__ rowptr, const int* __restrict__ cols,
    const float* __restrict__ dinv, int write8) {
    int i = blockIdx.x * 4 + (threadIdx.x >> 6);
    if (i >= NN) return;
    int lane = threadIdx.x & 63;
    const float di = dinv[i];
    const unsigned char* bin = src8 + lane * 8;

    float a0, a1, a2, a3, a4, a5, a6, a7;
    {   // self-loop from the bf16 copy
        uint4 u = *(const uint4*)(srcb + (size_t)i * FI + lane * 8);
        float s = di * di;
        a0 = s * blo(u.x); a1 = s * bhi(u.x);
        a2 = s * blo(u.y); a3 = s * bhi(u.y);
        a4 = s * blo(u.z); a5 = s * bhi(u.z);
        a6 = s * blo(u.w); a7 = s * bhi(u.w);
    }
    int k = rowptr[i], e = rowptr[i + 1];
    for (; k + 8 <= e; k += 8) {
        int c0 = cols[k + 0], c1 = cols[k + 1], c2 = cols[k + 2], c3 = cols[k + 3];
        int c4 = cols[k + 4], c5 = cols[k + 5], c6 = cols[k + 6], c7 = cols[k + 7];
        float w0 = dinv[c0], w1 = dinv[c1], w2 = dinv[c2], w3 = dinv[c3];
        float w4 = dinv[c4], w5 = dinv[c5], w6 = dinv[c6], w7 = dinv[c7];
        uint2 g0 = *(const uint2*)(bin + (size_t)c0 * FI);
        uint2 g1 = *(const uint2*)(bin + (size_t)c1 * FI);
        uint2 g2 = *(const uint2*)(bin + (size_t)c2 * FI);
        uint2 g3 = *(const uint2*)(bin + (size_t)c3 * FI);
        uint2 g4 = *(const uint2*)(bin + (size_t)c4 * FI);
        uint2 g5 = *(const uint2*)(bin + (size_t)c5 * FI);
        uint2 g6 = *(const uint2*)(bin + (size_t)c6 * FI);
        uint2 g7 = *(const uint2*)(bin + (size_t)c7 * FI);
        float v0 = di * w0, v1 = di * w1, v2 = di * w2, v3 = di * w3;
        float v4 = di * w4, v5 = di * w5, v6 = di * w6, v7 = di * w7;
        DEC8(g0, v0) DEC8(g1, v1) DEC8(g2, v2) DEC8(g3, v3)
        DEC8(g4, v4) DEC8(g5, v5) DEC8(g6, v6) DEC8(g7, v7)
    }
    for (; k < e; ++k) {
        int cc = cols[k];
        float v = di * dinv[cc];
        uint2 g = *(const uint2*)(bin + (size_t)cc * FI);
        DEC8(g, v)
    }
    uint4 o;
    o.x = ((unsigned int)f2b(a1) << 16) | f2b(a0);
    o.y = ((unsigned int)f2b(a3) << 16) | f2b(a2);
    o.z = ((unsigned int)f2b(a5) << 16) | f2b(a4);
    o.w = ((unsigned int)f2b(a7) << 16) | f2b(a6);
    *(uint4*)(dstb + lane * 8 + (size_t)i * FI) = o;
    if (write8) {
        unsigned r0 = (unsigned)__builtin_amdgcn_cvt_pk_fp8_f32(a0, a1, 0, false);
        r0 = (unsigned)__builtin_amdgcn_cvt_pk_fp8_f32(a2, a3, (int)r0, true);
        unsigned r1 = (unsigned)__builtin_amdgcn_cvt_pk_fp8_f32(a4, a5, 0, false);
        r1 = (unsigned)__builtin_amdgcn_cvt_pk_fp8_f32(a6, a7, (int)r1, true);
        uint2 o8; o8.x = r0; o8.y = r1;
        *(uint2*)(dst8 + lane * 8 + (size_t)i * FI) = o8;
    }
}

// ================= GEMM2 + log_softmax (fp32 out) =================
__global__ __launch_bounds__(256) void gemm2_kernel(
    const unsigned short* __restrict__ tb, const unsigned short* __restrict__ s1b,
    const unsigned short* __restrict__ s2b, const unsigned short* __restrict__ wct,
    const float* __restrict__ b2p, float* __restrict__ out) {
    int wave = threadIdx.x >> 6, lane = threadIdx.x & 63;
    int q = lane >> 4, c = lane & 15;
    int row0 = blockIdx.x * 64 + wave * 16;
    int ra = row0 + c; ra = ra < NN ? ra : NN - 1;
    const unsigned short* seg[3] = { tb + (size_t)ra * FI + q * 8,
                                     s1b + (size_t)ra * FI + q * 8,
                                     s2b + (size_t)ra * FI + q * 8 };
    const unsigned short* bp0 = wct + (size_t)(c)      * HW + q * 8;
    const unsigned short* bp1 = wct + (size_t)(16 + c) * HW + q * 8;
    const unsigned short* bp2 = wct + (size_t)(32 + c) * HW + q * 8;

    float4v A0 = {0.f,0.f,0.f,0.f}, A1 = {0.f,0.f,0.f,0.f}, A2 = {0.f,0.f,0.f,0.f};
    #pragma unroll
    for (int s = 0; s < 3; ++s) {
        const unsigned short* ap = seg[s];
        #pragma unroll 4
        for (int k0 = 0; k0 < 512; k0 += 32) {
            short8 a  = *(const short8*)(ap + k0);
            short8 b0 = *(const short8*)(bp0 + s * 512 + k0);
            short8 b1 = *(const short8*)(bp1 + s * 512 + k0);
            short8 b2 = *(const short8*)(bp2 + s * 512 + k0);
            A0 = __builtin_amdgcn_mfma_f32_16x16x32_bf16(a, b0, A0, 0, 0, 0);
            A1 = __builtin_amdgcn_mfma_f32_16x16x32_bf16(a, b1, A1, 0, 0, 0);
            A2 = __builtin_amdgcn_mfma_f32_16x16x32_bf16(a, b2, A2, 0, 0, 0);
        }
    }
    float bias0 = b2p[c];
    float bias1 = b2p[16 + c];
    float bias2 = (c < 8) ? b2p[32 + c] : 0.f;
    #pragma unroll
    for (int r = 0; r < 4; ++r) {
        float v0 = A0[r] + bias0;
        float v1 = A1[r] + bias1;
        float v2 = (c < 8) ? (A2[r] + bias2) : -1e30f;
        float mx = fmaxf(fmaxf(v0, v1), v2);
        #pragma unroll
        for (int d = 1; d < 16; d <<= 1) mx = fmaxf(mx, __shfl_xor(mx, d, 64));
        float s = __expf(v0 - mx) + __expf(v1 - mx) + ((c < 8) ? __expf(v2 - mx) : 0.f);
        #pragma unroll
        for (int d = 1; d < 16; d <<= 1) s += __shfl_xor(s, d, 64);
        float lse = mx + __logf(s);
        int rowg = row0 + q * 4 + r;
        if (rowg < NN) {
            out[(size_t)rowg * NC + c]      = v0 - lse;
            out[(size_t)rowg * NC + 16 + c] = v1 - lse;
            if (c < 8) out[(size_t)rowg * NC + 32 + c] = v2 - lse;
        }
    }
}

extern "C" void kernel_launch(void* const* d_in, const int* in_sizes, int n_in,
                              void* d_out, int out_size, void* d_ws, size_t ws_size,
                              hipStream_t stream) {
    const float* x  = (const float*)d_in[0];
    const int*   er = (const int*)d_in[1];
    const int*   ec = (const int*)d_in[2];
    const float* W1 = (const float*)d_in[3];
    const float* b1 = (const float*)d_in[4];
    const float* W2 = (const float*)d_in[5];
    const float* b2 = (const float*)d_in[6];
    float* out = (float*)d_out;

    char* p = (char*)d_ws;
    auto alloc = [&](size_t bytes) { char* r = p; p += (bytes + 255) & ~((size_t)255); return r; };
    int*      cntI   = (int*)      alloc((size_t)NN * 4);
    int*      degI   = (int*)      alloc((size_t)NN * 4);
    int*      rowptr = (int*)      alloc((size_t)(NN + 1) * 4);
    float*    dinv   = (float*)    alloc((size_t)NN * 4);
    int*      bsum   = (int*)      alloc((size_t)SCAN_NB * 4);
    int*      boff   = (int*)      alloc((size_t)SCAN_NB * 4);
    unsigned char* rank = (unsigned char*)alloc((size_t)NE);
    int*      colss  = (int*)      alloc((size_t)NE * 4);
    unsigned* hist_row = (unsigned*)alloc((size_t)CB * HWRD * 4);   // 12.8MB, dead after prep
    unsigned* hist_col = (unsigned*)alloc((size_t)CB * HWRD * 4);   // 12.8MB, dead after prep
    unsigned* base_w   = (unsigned*)alloc((size_t)CB * HWRD * 4);   // 12.8MB, dead after mega2
    unsigned short* w1t  = (unsigned short*)alloc((size_t)512 * 512 * 2);
    unsigned short* wct  = (unsigned short*)alloc((size_t)48 * HW * 2);
    unsigned short* xb   = (unsigned short*)alloc((size_t)NN * FI * 2);
    unsigned short* tbuf = (unsigned short*)alloc((size_t)NN * FI * 2);
    unsigned short* s1b  = (unsigned short*)alloc((size_t)NN * FI * 2);
    unsigned char*  s18  = (unsigned char*)alloc((size_t)NN * FI);
    // aliases: t8 over the (dead after prep) histograms; s2 over (dead after gemm1) xb
    unsigned char*  t8  = (unsigned char*)hist_row;   // 25.6MB needed; hist_row+hist_col = 25.6MB
    unsigned short* s2b = xb;

    // L1: independent prep work, count parts first
    mega1_kernel<<<2 * CB + 12500 + 1024 + 288, 256, 0, stream>>>(
        er, ec, x, W1, W2, rank, hist_row, hist_col, xb, w1t, wct);
    // L2: cross-block prefix (rows) + reduce (cols)
    prep_kernel<<<(2 * HWRD + 255) / 256, 256, 0, stream>>>(hist_row, hist_col, base_w, cntI, degI);
    // L3-5: rowptr scan + dinv
    scan1_kernel<<<SCAN_NB, 1024, 0, stream>>>(cntI, rowptr, bsum);
    scan2_kernel<<<1, 64, 0, stream>>>(bsum, boff);
    scan3_kernel<<<(NN + 255) / 256, 256, 0, stream>>>(rowptr, boff, degI, dinv);
    // L6: scatter (atomic-free) | gemm1  -- note t8 overwrites hist_* (dead), base_w still live for scatter
    mega2_kernel<<<NE / 256 + ((NN + 127) / 128) * 4, 256, 0, stream>>>(
        er, ec, rowptr, rank, (const unsigned char*)base_w, colss, xb, w1t, b1, tbuf, t8);
    // L7-8: SpMMs (fp8 gather)
    spmm_kernel<<<(NN + 3) / 4, 256, 0, stream>>>(t8, tbuf, s1b, s18, rowptr, colss, dinv, 1);
    spmm_kernel<<<(NN + 3) / 4, 256, 0, stream>>>(s18, s1b, s2b, (unsigned char*)nullptr, rowptr, colss, dinv, 0);
    // L9: final GEMM + log_softmax
    gemm2_kernel<<<(NN + 63) / 64, 256, 0, stream>>>(tbuf, s1b, s2b, wct, b2, out);
}